// Round 1
// baseline (1999.158 us; speedup 1.0000x reference)
//
#include <hip/hip_runtime.h>

#define EDIM 64

// ---------------------------------------------------------------------------
// Phase 1: triple SpMM scatter. One wave per nnz batch; lane = embedding dim.
// ga[r] += v*geo[c]; sa[r] += v*seq[c]; pa[r] += v*col[c]
// ---------------------------------------------------------------------------
__global__ __launch_bounds__(256) void spmm3_kernel(
    const int* __restrict__ rows, const int* __restrict__ cols,
    const float* __restrict__ vals,
    const float* __restrict__ geo, const float* __restrict__ seq,
    const float* __restrict__ colp,
    float* __restrict__ ga, float* __restrict__ sa, float* __restrict__ pa,
    int nnz) {
  const int lane = threadIdx.x & 63;
  const int wave = (int)((blockIdx.x * blockDim.x + threadIdx.x) >> 6);
  const int nWaves = (int)((gridDim.x * blockDim.x) >> 6);
  for (int base = wave * 64; base < nnz; base += nWaves * 64) {
    const int n = base + lane;
    int r_v = 0, c_v = 0;
    float v_v = 0.f;
    if (n < nnz) { r_v = rows[n]; c_v = cols[n]; v_v = vals[n]; }
    const int lim = min(64, nnz - base);
    for (int i = 0; i < lim; ++i) {
      const int r = __shfl(r_v, i);
      const int c = __shfl(c_v, i);
      const float v = __shfl(v_v, i);
      const size_t co = (size_t)c * EDIM + lane;
      const size_t ro = (size_t)r * EDIM + lane;
      atomicAdd(&ga[ro], v * geo[co]);
      atomicAdd(&sa[ro], v * seq[co]);
      atomicAdd(&pa[ro], v * colp[co]);
    }
  }
}

// ---------------------------------------------------------------------------
// Phase 2: fused msg construction + msg @ W^T + bias + gated user merge.
// W^T staged in LDS as wt[f][e] (448x64 f32 = 114688 B, dynamic LDS).
// One wave handles UPW users at a time; lane = output dim e.
// msg order: [ga, sa, pa, ga*sa, ga*pa, sa*pa, ga*sa*pa]
// ---------------------------------------------------------------------------
#define UPW 4
__global__ __launch_bounds__(512) void fusion_kernel(
    const float* __restrict__ ga, const float* __restrict__ sa,
    const float* __restrict__ pa, const float* __restrict__ uemb,
    const float* __restrict__ W,  // [64][448] row-major
    const float* __restrict__ b,  // [64]
    float* __restrict__ hg,       // [U][64]
    int n_users) {
  extern __shared__ float wt[];  // [448][64]
  const int tid = threadIdx.x;
  const int nthr = blockDim.x;
  for (int idx = tid; idx < 64 * 448; idx += nthr) {
    const int e = idx / 448;
    const int f = idx - e * 448;
    wt[f * 64 + e] = W[idx];  // coalesced global read, scattered LDS write
  }
  __syncthreads();

  const int lane = tid & 63;
  const int wavesPerBlock = nthr >> 6;
  const int waveGlobal = blockIdx.x * wavesPerBlock + (tid >> 6);
  const int nWaves = gridDim.x * wavesPerBlock;
  const float bias = b[lane];

  for (int u0 = waveGlobal * UPW; u0 < n_users; u0 += nWaves * UPW) {
    const int cnt = min(UPW, n_users - u0);
    float g[UPW], s[UPW], p[UPW], ue[UPW], acc[UPW];
#pragma unroll
    for (int i = 0; i < UPW; ++i) {
      const int u = u0 + (i < cnt ? i : 0);
      const size_t off = (size_t)u * EDIM + lane;
      g[i] = ga[off]; s[i] = sa[off]; p[i] = pa[off]; ue[i] = uemb[off];
      acc[i] = 0.f;
    }
    for (int j = 0; j < 64; ++j) {
      const int base = j * 64 + lane;
      const float w0 = wt[base];
      const float w1 = wt[base + 1 * 4096];
      const float w2 = wt[base + 2 * 4096];
      const float w3 = wt[base + 3 * 4096];
      const float w4 = wt[base + 4 * 4096];
      const float w5 = wt[base + 5 * 4096];
      const float w6 = wt[base + 6 * 4096];
#pragma unroll
      for (int i = 0; i < UPW; ++i) {
        const float gj = __shfl(g[i], j);
        const float sj = __shfl(s[i], j);
        const float pj = __shfl(p[i], j);
        const float gs = gj * sj;
        const float gp = gj * pj;
        const float sp = sj * pj;
        const float gsp = gs * pj;
        acc[i] += w0 * gj + w1 * sj + w2 * pj + w3 * gs + w4 * gp + w5 * sp +
                  w6 * gsp;
      }
    }
#pragma unroll
    for (int i = 0; i < UPW; ++i) {
      if (i < cnt) {
        const float me = acc[i] + bias;
        const float u_ = ue[i];
        const size_t off = (size_t)(u0 + i) * EDIM + lane;
        hg[off] = me + u_ + me * u_;  // me + u + me*u
      }
    }
  }
}

// ---------------------------------------------------------------------------
// Phase 3: transpose SpMM scatter with fused mean scale (L/2) into d_out.
// out[c] += scale * pu_v * hg[r]
// ---------------------------------------------------------------------------
__global__ __launch_bounds__(256) void spmmT_kernel(
    const int* __restrict__ rows, const int* __restrict__ cols,
    const float* __restrict__ pu_vals, const float* __restrict__ hg,
    float* __restrict__ out, const int* __restrict__ num_layers, int nnz) {
  const float scale = 0.5f * (float)num_layers[0];
  const int lane = threadIdx.x & 63;
  const int wave = (int)((blockIdx.x * blockDim.x + threadIdx.x) >> 6);
  const int nWaves = (int)((gridDim.x * blockDim.x) >> 6);
  for (int base = wave * 64; base < nnz; base += nWaves * 64) {
    const int n = base + lane;
    int r_v = 0, c_v = 0;
    float v_v = 0.f;
    if (n < nnz) { r_v = rows[n]; c_v = cols[n]; v_v = pu_vals[n]; }
    const int lim = min(64, nnz - base);
    for (int i = 0; i < lim; ++i) {
      const int r = __shfl(r_v, i);
      const int c = __shfl(c_v, i);
      const float v = __shfl(v_v, i) * scale;
      atomicAdd(&out[(size_t)c * EDIM + lane],
                v * hg[(size_t)r * EDIM + lane]);
    }
  }
}

// ---------------------------------------------------------------------------
// Phase 4: out += init (final mean, scale already folded into phase 3)
// ---------------------------------------------------------------------------
__global__ __launch_bounds__(256) void add_init_kernel(
    const float* __restrict__ init, float* __restrict__ out, int n4) {
  const int stride = gridDim.x * blockDim.x;
  const float4* in4 = (const float4*)init;
  float4* o4 = (float4*)out;
  for (int i = blockIdx.x * blockDim.x + threadIdx.x; i < n4; i += stride) {
    float4 a = in4[i];
    float4 o = o4[i];
    o.x += a.x; o.y += a.y; o.z += a.z; o.w += a.w;
    o4[i] = o;
  }
}

extern "C" void kernel_launch(void* const* d_in, const int* in_sizes, int n_in,
                              void* d_out, int out_size, void* d_ws,
                              size_t ws_size, hipStream_t stream) {
  const float* init = (const float*)d_in[0];
  const float* colp = (const float*)d_in[1];
  const float* geo  = (const float*)d_in[2];
  const float* seq  = (const float*)d_in[3];
  const float* uemb = (const float*)d_in[4];
  const int* up_rows = (const int*)d_in[5];
  const int* up_cols = (const int*)d_in[6];
  const float* up_vals = (const float*)d_in[7];
  const float* pu_vals = (const float*)d_in[8];
  const float* W = (const float*)d_in[9];
  const float* b = (const float*)d_in[10];
  const int* num_layers = (const int*)d_in[11];

  const int U = in_sizes[4] / EDIM;
  const int P = in_sizes[0] / EDIM;
  const int NNZ = in_sizes[5];

  float* ga = (float*)d_ws;
  float* sa = ga + (size_t)U * EDIM;
  float* pa = sa + (size_t)U * EDIM;
  float* hg = pa + (size_t)U * EDIM;
  float* out = (float*)d_out;

  // zero accumulators (ws/out are poisoned, not re-zeroed between replays)
  hipMemsetAsync(ga, 0, (size_t)3 * U * EDIM * sizeof(float), stream);
  hipMemsetAsync(out, 0, (size_t)P * EDIM * sizeof(float), stream);

  spmm3_kernel<<<2048, 256, 0, stream>>>(up_rows, up_cols, up_vals, geo, seq,
                                         colp, ga, sa, pa, NNZ);

  fusion_kernel<<<256, 512, 448 * 64 * sizeof(float), stream>>>(
      ga, sa, pa, uemb, W, b, hg, U);

  spmmT_kernel<<<2048, 256, 0, stream>>>(up_rows, up_cols, pu_vals, hg, out,
                                         num_layers, NNZ);

  add_init_kernel<<<2048, 256, 0, stream>>>(init, out, (P * EDIM) / 4);
}

// Round 2
// 1210.349 us; speedup vs baseline: 1.6517x; 1.6517x over previous
//
#include <hip/hip_runtime.h>

#define EDIM 64
#define SCAN_BLK 256
#define SCAN_CHUNK 2048  // 8 elements per thread

// ---------------------------------------------------------------------------
// CSR/CSC build: histogram -> hierarchical exclusive scan -> cursor scatter.
// ptr arrays double as counters, then exclusive offsets, then (post-scatter)
// inclusive row ends: start(r) = (r==0)?0:ptr[r-1], end(r)=ptr[r].
// ---------------------------------------------------------------------------
__global__ __launch_bounds__(256) void hist_kernel(
    const int* __restrict__ rows, const int* __restrict__ cols,
    int* __restrict__ cntU, int* __restrict__ cntP, int nnz) {
  const int stride = gridDim.x * blockDim.x;
  for (int i = blockIdx.x * blockDim.x + threadIdx.x; i < nnz; i += stride) {
    atomicAdd(&cntU[rows[i]], 1);
    atomicAdd(&cntP[cols[i]], 1);
  }
}

__global__ __launch_bounds__(SCAN_BLK) void scan_reduce_kernel(
    const int* __restrict__ cnt, int n, int* __restrict__ bsum) {
  __shared__ int wsh[SCAN_BLK / 64];
  const int lane = threadIdx.x & 63, wid = threadIdx.x >> 6;
  const int base = blockIdx.x * SCAN_CHUNK + threadIdx.x * 8;
  int s = 0;
#pragma unroll
  for (int k = 0; k < 8; ++k) {
    const int idx = base + k;
    if (idx < n) s += cnt[idx];
  }
  for (int d = 32; d; d >>= 1) s += __shfl_down(s, d);
  if (lane == 0) wsh[wid] = s;
  __syncthreads();
  if (threadIdx.x == 0) {
    int t = 0;
    for (int w = 0; w < SCAN_BLK / 64; ++w) t += wsh[w];
    bsum[blockIdx.x] = t;
  }
}

__global__ void scan_top_kernel(int* __restrict__ bsum, int nb) {
  __shared__ int tmp[256];
  if ((int)threadIdx.x < nb) tmp[threadIdx.x] = bsum[threadIdx.x];
  __syncthreads();
  if (threadIdx.x == 0) {
    int run = 0;
    for (int i = 0; i < nb; ++i) { const int c = tmp[i]; tmp[i] = run; run += c; }
  }
  __syncthreads();
  if ((int)threadIdx.x < nb) bsum[threadIdx.x] = tmp[threadIdx.x];
}

__global__ __launch_bounds__(SCAN_BLK) void scan_apply_kernel(
    int* __restrict__ ptr, int n, const int* __restrict__ bsum) {
  __shared__ int wsum[SCAN_BLK / 64];
  const int lane = threadIdx.x & 63, wid = threadIdx.x >> 6;
  const int base = blockIdx.x * SCAN_CHUNK + threadIdx.x * 8;
  int v[8];
  int tot = 0;
#pragma unroll
  for (int k = 0; k < 8; ++k) {
    const int idx = base + k;
    v[k] = (idx < n) ? ptr[idx] : 0;
    tot += v[k];
  }
  int sc = tot;  // inclusive wave scan
  for (int d = 1; d < 64; d <<= 1) {
    const int o = __shfl_up(sc, d);
    if (lane >= d) sc += o;
  }
  if (lane == 63) wsum[wid] = sc;
  __syncthreads();
  int woff = 0;
  for (int w = 0; w < wid; ++w) woff += wsum[w];
  int run = bsum[blockIdx.x] + woff + sc - tot;  // exclusive offset
#pragma unroll
  for (int k = 0; k < 8; ++k) {
    const int idx = base + k;
    if (idx < n) ptr[idx] = run;
    run += v[k];
  }
}

__global__ __launch_bounds__(256) void scatter_kernel(
    const int* __restrict__ rows, const int* __restrict__ cols,
    int* __restrict__ ptrU, int* __restrict__ ptrP,
    int* __restrict__ permU, int* __restrict__ permP, int nnz) {
  const int stride = gridDim.x * blockDim.x;
  for (int i = blockIdx.x * blockDim.x + threadIdx.x; i < nnz; i += stride) {
    const int pu = atomicAdd(&ptrU[rows[i]], 1);
    permU[pu] = i;
    const int pp = atomicAdd(&ptrP[cols[i]], 1);
    permP[pp] = i;
  }
}

// ---------------------------------------------------------------------------
// Gather per user (no atomics) + fused msg @ W^T + bias + gated merge.
// W^T in LDS (448x64 f32 = 114688 B). 1024 thr/block -> 16 waves/CU,
// 1 block/CU (LDS-capped). Each wave: gather 4 users, then fuse 4 at once.
// ---------------------------------------------------------------------------
#define FBLK 1024
__global__ __launch_bounds__(FBLK) void user_gather_fuse_kernel(
    const int* __restrict__ ptrU, const int* __restrict__ permU,
    const int* __restrict__ cols, const float* __restrict__ vals,
    const float* __restrict__ geo, const float* __restrict__ seq,
    const float* __restrict__ colp, const float* __restrict__ uemb,
    const float* __restrict__ W, const float* __restrict__ b,
    float* __restrict__ hg, int U) {
  extern __shared__ float wt[];  // [448][64]
  for (int idx = threadIdx.x; idx < 448 * 64; idx += FBLK) {
    const int e = idx / 448;
    const int f = idx - e * 448;
    wt[f * 64 + e] = W[idx];
  }
  __syncthreads();
  const int lane = threadIdx.x & 63;
  const int wv = blockIdx.x * (FBLK / 64) + (threadIdx.x >> 6);
  const int nW = gridDim.x * (FBLK / 64);
  const float bias = b[lane];

  for (int u0 = wv * 4; u0 < U; u0 += nW * 4) {
    const int cnt = min(4, U - u0);
    float g[4] = {0, 0, 0, 0}, s[4] = {0, 0, 0, 0}, p[4] = {0, 0, 0, 0};
    for (int i = 0; i < cnt; ++i) {
      const int u = u0 + i;
      const int start = (u == 0) ? 0 : ptrU[u - 1];
      const int end = ptrU[u];
      for (int k0 = start; k0 < end; k0 += 64) {
        int c_v = 0;
        float v_v = 0.f;
        const int kk = k0 + lane;
        if (kk < end) {
          const int id = permU[kk];
          c_v = cols[id];
          v_v = vals[id];
        }
        const int lim = min(64, end - k0);
        for (int t = 0; t < lim; ++t) {
          const int cc = __shfl(c_v, t);
          const float vv = __shfl(v_v, t);
          const size_t off = (size_t)cc * EDIM + lane;
          g[i] += vv * geo[off];
          s[i] += vv * seq[off];
          p[i] += vv * colp[off];
        }
      }
    }
    float acc[4] = {0, 0, 0, 0};
    for (int j = 0; j < 64; ++j) {
      const int basej = j * 64 + lane;
      const float w0 = wt[basej];
      const float w1 = wt[basej + 1 * 4096];
      const float w2 = wt[basej + 2 * 4096];
      const float w3 = wt[basej + 3 * 4096];
      const float w4 = wt[basej + 4 * 4096];
      const float w5 = wt[basej + 5 * 4096];
      const float w6 = wt[basej + 6 * 4096];
#pragma unroll
      for (int i = 0; i < 4; ++i) {
        const float gj = __shfl(g[i], j);
        const float sj = __shfl(s[i], j);
        const float pj = __shfl(p[i], j);
        const float gs = gj * sj, gp = gj * pj, sp = sj * pj;
        acc[i] += w0 * gj + w1 * sj + w2 * pj + w3 * gs + w4 * gp + w5 * sp +
                  w6 * gs * pj;
      }
    }
#pragma unroll
    for (int i = 0; i < 4; ++i) {
      if (i < cnt) {
        const float me = acc[i] + bias;
        const size_t off = (size_t)(u0 + i) * EDIM + lane;
        const float ue = uemb[off];
        hg[off] = me + ue + me * ue;
      }
    }
  }
}

// ---------------------------------------------------------------------------
// Gather per POI (transpose side), fused with mean: out = init + (L/2)*acc.
// ---------------------------------------------------------------------------
__global__ __launch_bounds__(256) void poi_gather_kernel(
    const int* __restrict__ ptrP, const int* __restrict__ permP,
    const int* __restrict__ rows, const float* __restrict__ pu_vals,
    const float* __restrict__ hg, const float* __restrict__ init,
    const int* __restrict__ num_layers, float* __restrict__ out, int P) {
  const float scale = 0.5f * (float)num_layers[0];
  const int lane = threadIdx.x & 63;
  const int wv = blockIdx.x * 4 + (threadIdx.x >> 6);
  const int nW = gridDim.x * 4;
  for (int c = wv; c < P; c += nW) {
    const int start = (c == 0) ? 0 : ptrP[c - 1];
    const int end = ptrP[c];
    float acc = 0.f;
    for (int k0 = start; k0 < end; k0 += 64) {
      int r_v = 0;
      float v_v = 0.f;
      const int kk = k0 + lane;
      if (kk < end) {
        const int id = permP[kk];
        r_v = rows[id];
        v_v = pu_vals[id];
      }
      const int lim = min(64, end - k0);
      for (int t = 0; t < lim; ++t) {
        const int rr = __shfl(r_v, t);
        const float vv = __shfl(v_v, t);
        acc += vv * hg[(size_t)rr * EDIM + lane];
      }
    }
    const size_t off = (size_t)c * EDIM + lane;
    out[off] = init[off] + scale * acc;
  }
}

extern "C" void kernel_launch(void* const* d_in, const int* in_sizes, int n_in,
                              void* d_out, int out_size, void* d_ws,
                              size_t ws_size, hipStream_t stream) {
  const float* init = (const float*)d_in[0];
  const float* colp = (const float*)d_in[1];
  const float* geo = (const float*)d_in[2];
  const float* seq = (const float*)d_in[3];
  const float* uemb = (const float*)d_in[4];
  const int* up_rows = (const int*)d_in[5];
  const int* up_cols = (const int*)d_in[6];
  const float* up_vals = (const float*)d_in[7];
  const float* pu_vals = (const float*)d_in[8];
  const float* W = (const float*)d_in[9];
  const float* b = (const float*)d_in[10];
  const int* num_layers = (const int*)d_in[11];

  const int U = in_sizes[4] / EDIM;
  const int P = in_sizes[0] / EDIM;
  const int NNZ = in_sizes[5];

  int* ptrU = (int*)d_ws;        // U counters -> offsets -> ends
  int* ptrP = ptrU + U;          // P
  int* permU = ptrP + P;         // NNZ
  int* permP = permU + NNZ;      // NNZ
  int* bsumU = permP + NNZ;      // 256
  int* bsumP = bsumU + 256;      // 256
  float* hg = (float*)(bsumP + 256);  // U*64
  float* out = (float*)d_out;

  const int nbU = (U + SCAN_CHUNK - 1) / SCAN_CHUNK;
  const int nbP = (P + SCAN_CHUNK - 1) / SCAN_CHUNK;

  hipMemsetAsync(ptrU, 0, (size_t)(U + P) * sizeof(int), stream);

  hist_kernel<<<1024, 256, 0, stream>>>(up_rows, up_cols, ptrU, ptrP, NNZ);

  scan_reduce_kernel<<<nbU, SCAN_BLK, 0, stream>>>(ptrU, U, bsumU);
  scan_reduce_kernel<<<nbP, SCAN_BLK, 0, stream>>>(ptrP, P, bsumP);
  scan_top_kernel<<<1, 256, 0, stream>>>(bsumU, nbU);
  scan_top_kernel<<<1, 256, 0, stream>>>(bsumP, nbP);
  scan_apply_kernel<<<nbU, SCAN_BLK, 0, stream>>>(ptrU, U, bsumU);
  scan_apply_kernel<<<nbP, SCAN_BLK, 0, stream>>>(ptrP, P, bsumP);

  scatter_kernel<<<1024, 256, 0, stream>>>(up_rows, up_cols, ptrU, ptrP,
                                           permU, permP, NNZ);

  user_gather_fuse_kernel<<<256, FBLK, 448 * 64 * sizeof(float), stream>>>(
      ptrU, permU, up_cols, up_vals, geo, seq, colp, uemb, W, b, hg, U);

  poi_gather_kernel<<<2048, 256, 0, stream>>>(ptrP, permP, up_rows, pu_vals,
                                              hg, init, num_layers, out, P);
}